// Round 9
// baseline (285.667 us; speedup 1.0000x reference)
//
#include <hip/hip_runtime.h>

// Shapes fixed by the reference: B=8, C=128, H=W=64 -> S=4096. All I/O fp32.
#define BB 8
#define CC 128
#define SS 4096
#define KT 64
#define SCL2 0.022542120f      // log2(e)/64  (p = exp2(s*SCL2) = exp(s/64))

typedef __attribute__((ext_vector_type(8)))  short sh8;    // 8 bf16 (MFMA A/B frag)
typedef __attribute__((ext_vector_type(4)))  float f32x4;
typedef __attribute__((ext_vector_type(16))) float f32x16; // 32x32 MFMA C/D frag

__device__ __forceinline__ float b2f(unsigned short u) {
    union { unsigned int i; float f; } x; x.i = ((unsigned int)u) << 16; return x.f;
}
__device__ __forceinline__ unsigned short f2b(float f) {  // RNE
    union { float f; unsigned int i; } x; x.f = f;
    unsigned int r = x.i + 0x7fff + ((x.i >> 16) & 1);
    return (unsigned short)(r >> 16);
}
__device__ __forceinline__ unsigned short rhu(float f) {  // round-half-up, 2 VALU
    union { float f; unsigned int i; } x; x.f = f;
    return (unsigned short)((x.i + 0x8000) >> 16);
}

// async 16B global->LDS DMA (lane i writes lds_base + i*16; LDS base wave-uniform)
__device__ __forceinline__ void dma16(const void* g, void* l) {
    __builtin_amdgcn_global_load_lds((const __attribute__((address_space(1))) void*)g,
                                     (__attribute__((address_space(3))) void*)l,
                                     16, 0, 0);
}

// ---------------------------------------------------------------------------
// Fused aux (unchanged from R8). grid=(64,8,3): z=0 Q-proj, z=1 K-proj,
// z=2 V fp32->bf16 convert.
// ---------------------------------------------------------------------------
__global__ __launch_bounds__(256) void aux_kernel(
    const float* __restrict__ qimg, const float* __restrict__ kimg,
    const float* __restrict__ vimg,
    const float* __restrict__ Wq, const float* __restrict__ bq,
    const float* __restrict__ Wk, const float* __restrict__ bk,
    unsigned short* __restrict__ Qbuf, unsigned short* __restrict__ Kbuf,
    unsigned short* __restrict__ Vbuf)
{
    const int tid = threadIdx.x;
    const int z   = blockIdx.z;

    if (z == 2) {
        const size_t base = ((size_t)blockIdx.y * 64 + blockIdx.x) * 8192 + tid * 4;
        #pragma unroll
        for (int it = 0; it < 8; ++it) {
            const size_t i = base + (size_t)it * 1024;
            float4 v = *(const float4*)(vimg + i);
            ushort4 o;
            o.x = f2b(v.x); o.y = f2b(v.y); o.z = f2b(v.z); o.w = f2b(v.w);
            *(ushort4*)(Vbuf + i) = o;
        }
        return;
    }

    __shared__ float ilds[128 * 69];

    const float* img  = (z == 0) ? qimg : kimg;
    const float* Wf   = (z == 0) ? Wq : Wk;
    const float* bias = (z == 0) ? bq : bk;
    unsigned short* outTok = (z == 0) ? Qbuf : Kbuf;

    const int wave = tid >> 6;
    const int lane = tid & 63;
    const int l15  = lane & 15;
    const int quad = lane >> 4;
    const int b     = blockIdx.y;
    const int stile = blockIdx.x;

    const float* gbase = img + (size_t)b * CC * SS + stile * 64;
    #pragma unroll
    for (int i = 0; i < 8; ++i) {
        const int l = tid + 256 * i;
        const int row = l >> 4, col = (l & 15) * 4;
        float4 v = *(const float4*)(gbase + (size_t)row * SS + col);
        float* d = ilds + row * 69 + col;
        d[0] = v.x; d[1] = v.y; d[2] = v.z; d[3] = v.w;
    }
    __syncthreads();

    const int tcol = wave * 16 + l15;
    sh8 a[4];
    #pragma unroll
    for (int kk = 0; kk < 4; ++kk)
        #pragma unroll
        for (int j = 0; j < 8; ++j)
            a[kk][j] = (short)rhu(ilds[(32 * kk + quad * 8 + j) * 69 + tcol]);

    f32x4 acc[8];
    #pragma unroll
    for (int nt = 0; nt < 8; ++nt) acc[nt] = (f32x4){0.f, 0.f, 0.f, 0.f};

    #pragma unroll
    for (int nt = 0; nt < 8; ++nt) {
        const float* wp = Wf + (size_t)(16 * nt + l15) * CC + quad * 8;
        #pragma unroll
        for (int kk = 0; kk < 4; ++kk) {
            float4 w0 = *(const float4*)(wp + 32 * kk);
            float4 w1 = *(const float4*)(wp + 32 * kk + 4);
            sh8 bfr;
            bfr[0] = (short)rhu(w0.x); bfr[1] = (short)rhu(w0.y);
            bfr[2] = (short)rhu(w0.z); bfr[3] = (short)rhu(w0.w);
            bfr[4] = (short)rhu(w1.x); bfr[5] = (short)rhu(w1.y);
            bfr[6] = (short)rhu(w1.z); bfr[7] = (short)rhu(w1.w);
            acc[nt] = __builtin_amdgcn_mfma_f32_16x16x32_bf16(a[kk], bfr, acc[nt], 0, 0, 0);
        }
    }

    #pragma unroll
    for (int nt = 0; nt < 8; ++nt) {
        const int o = 16 * nt + l15;
        const float bv = bias[o];
        #pragma unroll
        for (int r = 0; r < 4; ++r) {
            const int s = stile * 64 + wave * 16 + quad * 4 + r;
            outTok[((size_t)b * SS + s) * CC + o] = f2b(acc[nt][r] + bv);
        }
    }
}

// ---------------------------------------------------------------------------
// Flash attention with 32x32x16 MFMA + interleaved (DMA-gather) LDS layouts.
// Wave w: QK tile (qhalf=w>>1, kthalf=w&1); PV tile (qhalf=w>>1, chalf=w&1).
// LDS layouts (conflict-free frag reads, contiguous 512B per half-wave):
//   K: phys = chunk*1024 + token*16         (chunk = channel-16B-chunk, 0..15)
//   V: phys = ktchunk*2048 + ch*16          (ktchunk = kt-16B-chunk, 0..7)
//   P: phys = ktc*1024 + (q^ktc)*16 + (kt&7)*2  (write 2-way free, read bijective)
// Map: [0,16K) kb0 [16K,32K) kb1 [32K,48K) vb0 [48K,64K) vb1
//      [64K,72K) P  [73728,74240) lsums float[2][2][32]
// 2 barriers/iter: (a) tiles resident, (b) P visible (cross-wave PV).
// NOTE: 32x32x16 A/B layout assumed m=lane&31, k=8*(lane>>5)+j (extrapolated
// from verified 16x16x32 pattern; C/D layout is the verified m74/m101 one).
// ---------------------------------------------------------------------------
__global__ __launch_bounds__(256, 2) void attn_kernel(
    const unsigned short* __restrict__ Qbuf,  // (B,S,C) bf16 token-major
    const unsigned short* __restrict__ Kbuf,  // (B,S,C) bf16 token-major
    const unsigned short* __restrict__ Vbuf,  // (B,C,S) bf16 channel-major
    float* __restrict__ out)                  // (B,C,S) fp32 channel-major
{
    __shared__ __align__(16) unsigned char smem[74240];
    unsigned char* pLds  = smem + 65536;
    float* lsumsLds      = (float*)(smem + 73728);   // [qh][kth][row31]

    const int tid  = threadIdx.x;
    const int wave = tid >> 6;
    const int lane = tid & 63;
    const int l31  = lane & 31;
    const int h    = lane >> 5;
    const int qh    = wave >> 1;
    const int kth   = wave & 1;     // QK role
    const int chalf = wave & 1;     // PV role
    const int b     = blockIdx.y;
    const int qtile = blockIdx.x;

    const char* kbp = (const char*)(Kbuf + (size_t)b * SS * CC);
    const char* vbp = (const char*)(Vbuf + (size_t)b * CC * SS);

    // Q A-frags (32 q-rows per wave), loaded once: m = l31, k = 16*ks + 8*h + j
    sh8 aq[8];
    {
        const unsigned short* qp = Qbuf + ((size_t)b * SS + qtile * 64 + 32 * qh + l31) * CC + 8 * h;
        #pragma unroll
        for (int ks = 0; ks < 8; ++ks) aq[ks] = *(const sh8*)(qp + 16 * ks);
    }

    // DMA gather offsets (bytes). K slot = (wave*4+j)*64+lane -> (t=lane, c=4w+j).
    // V slot -> (ch = 64*(j&1)+lane, ktc = 2*wave + (j>>1)).
    int kGO[4], vGO[4];
    #pragma unroll
    for (int j = 0; j < 4; ++j) {
        kGO[j] = lane * 256 + (wave * 4 + j) * 16;
        vGO[j] = (64 * (j & 1) + lane) * 8192 + (2 * wave + (j >> 1)) * 16;
    }

    f32x16 oacc[2];
    #pragma unroll
    for (int ct = 0; ct < 2; ++ct)
        #pragma unroll
        for (int r = 0; r < 16; ++r) oacc[ct][r] = 0.f;
    float lsum[16];
    #pragma unroll
    for (int r = 0; r < 16; ++r) lsum[r] = 0.f;

    // prologue: stage tile 0 into buffer 0
    #pragma unroll
    for (int j = 0; j < 4; ++j) {
        dma16(kbp + kGO[j], smem + (wave * 4 + j) * 1024);
        dma16(vbp + vGO[j], smem + 32768 + (wave * 4 + j) * 1024);
    }

    for (int it = 0; it < SS / KT; ++it) {
        const int cur = (it & 1) * 16384;
        unsigned char* kb = smem + cur;
        unsigned char* vb = smem + 32768 + cur;

        __syncthreads();   // (a) tile(it) resident; WAR for buffer 1-cur

        if (it + 1 < SS / KT) {
            const int nxt = 16384 - cur;
            const char* gk = kbp + (size_t)(it + 1) * 16384;
            const char* gv = vbp + (size_t)(it + 1) * 128;
            #pragma unroll
            for (int j = 0; j < 4; ++j) {
                dma16(gk + kGO[j], smem + nxt + (wave * 4 + j) * 1024);
                dma16(gv + vGO[j], smem + 32768 + nxt + (wave * 4 + j) * 1024);
            }
        }

        // --- S(32q x 32kt) = Q K^T : B-frag n=kt=32*kth+l31, k=16*ks+8*h+j ---
        f32x16 sacc;
        #pragma unroll
        for (int r = 0; r < 16; ++r) sacc[r] = 0.f;
        #pragma unroll
        for (int ks = 0; ks < 8; ++ks) {
            sh8 kf = *(const sh8*)(kb + (2 * ks + h) * 1024 + (32 * kth + l31) * 16);
            sacc = __builtin_amdgcn_mfma_f32_32x32x16_bf16(aq[ks], kf, sacc, 0, 0, 0);
        }

        // --- softmax (no max) -> P. C/D row31 = (reg&3)+8*(reg>>2)+4*h ---
        {
            const int ktcw = 4 * kth + (l31 >> 3);
            const int k7o  = (l31 & 7) * 2;
            unsigned char* pb = pLds + ktcw * 1024 + qh * 512 + k7o;
            #pragma unroll
            for (int reg = 0; reg < 16; ++reg) {
                float p = exp2f(sacc[reg] * SCL2);
                lsum[reg] += p;
                const int q31 = (reg & 3) + 8 * (reg >> 2) + 4 * h;
                *(unsigned short*)(pb + ((q31 ^ ktcw) << 4)) = rhu(p);
            }
        }

        __syncthreads();   // (b) P visible to sibling kth wave (drains DMA too)

        // --- O(32q x 64ch) += P V : A=P, B=V ---
        #pragma unroll
        for (int ks = 0; ks < 4; ++ks) {
            const int ktc = 2 * ks + h;
            sh8 ap = *(const sh8*)(pLds + ktc * 1024 + qh * 512 + ((l31 ^ ktc) << 4));
            #pragma unroll
            for (int ct = 0; ct < 2; ++ct) {
                sh8 bv = *(const sh8*)(vb + ktc * 2048 + (64 * chalf + 32 * ct + l31) * 16);
                oacc[ct] = __builtin_amdgcn_mfma_f32_32x32x16_bf16(ap, bv, oacc[ct], 0, 0, 0);
            }
        }
    }

    // --- reduce lsum over the 32 kt-cols of this wave's half, publish to LDS ---
    #pragma unroll
    for (int reg = 0; reg < 16; ++reg) {
        float v = lsum[reg];
        #pragma unroll
        for (int m = 16; m >= 1; m >>= 1) v += __shfl_xor(v, m, 64);  // within 32-half
        lsum[reg] = v;
    }
    if (l31 == 0) {
        #pragma unroll
        for (int reg = 0; reg < 16; ++reg) {
            const int r31 = (reg & 3) + 8 * (reg >> 2) + 4 * h;
            lsumsLds[(qh * 2 + kth) * 32 + r31] = lsum[reg];
        }
    }
    __syncthreads();   // lsums visible; K/V/P reads all done -> can alias smem

    // --- epilogue: normalize, residual, coalesced transpose write ---
    float (*oLds)[132] = (float(*)[132])smem;   // 64*132*4 = 33,792 B (aliases K/V)
    #pragma unroll
    for (int ct = 0; ct < 2; ++ct) {
        const int ch = 64 * chalf + 32 * ct + l31;
        #pragma unroll
        for (int reg = 0; reg < 16; ++reg) {
            const int r31  = (reg & 3) + 8 * (reg >> 2) + 4 * h;
            const int qloc = 32 * qh + r31;
            const float lt = lsumsLds[(qh * 2 + 0) * 32 + r31]
                           + lsumsLds[(qh * 2 + 1) * 32 + r31];
            const float resid = b2f(Qbuf[((size_t)b * SS + qtile * 64 + qloc) * CC + ch]);
            oLds[qloc][ch] = oacc[ct][reg] / lt + resid;
        }
    }
    __syncthreads();
    for (int idx = tid; idx < 64 * 128; idx += 256) {
        const int c = idx >> 6, q = idx & 63;
        out[((size_t)b * CC + c) * SS + qtile * 64 + q] = oLds[q][c];
    }
}

extern "C" void kernel_launch(void* const* d_in, const int* in_sizes, int n_in,
                              void* d_out, int out_size, void* d_ws, size_t ws_size,
                              hipStream_t stream) {
    const float* qimg = (const float*)d_in[0];
    const float* kimg = (const float*)d_in[1];
    const float* vimg = (const float*)d_in[2];
    const float* Wq   = (const float*)d_in[3];
    const float* bq   = (const float*)d_in[4];
    const float* Wk   = (const float*)d_in[5];
    const float* bk   = (const float*)d_in[6];
    float* out = (float*)d_out;

    unsigned short* Qbuf = (unsigned short*)d_ws;                    // 8.39 MB
    unsigned short* Kbuf = Qbuf + (size_t)BB * SS * CC;              // 8.39 MB
    unsigned short* Vbuf = Kbuf + (size_t)BB * SS * CC;              // 8.39 MB

    aux_kernel<<<dim3(SS / 64, BB, 3), 256, 0, stream>>>(
        qimg, kimg, vimg, Wq, bq, Wk, bk, Qbuf, Kbuf, Vbuf);
    attn_kernel<<<dim3(SS / 64, BB), 256, 0, stream>>>(Qbuf, Kbuf, Vbuf, out);
}

// Round 10
// 232.769 us; speedup vs baseline: 1.2273x; 1.2273x over previous
//
#include <hip/hip_runtime.h>

// Shapes fixed by the reference: B=8, C=128, H=W=64 -> S=4096. All I/O fp32.
#define BB 8
#define CC 128
#define SS 4096
#define KT 64
#define SCL2 0.0225421100f     // log2(e)/64  (p = exp2(s*SCL2) = exp(s/64))

typedef __attribute__((ext_vector_type(8)))  short sh8;    // 8 bf16 (MFMA A/B frag)
typedef __attribute__((ext_vector_type(4)))  float f32x4;
typedef __attribute__((ext_vector_type(16))) float f32x16; // 32x32 MFMA C/D frag

__device__ __forceinline__ float b2f(unsigned short u) {
    union { unsigned int i; float f; } x; x.i = ((unsigned int)u) << 16; return x.f;
}
__device__ __forceinline__ unsigned short f2b(float f) {  // RNE
    union { float f; unsigned int i; } x; x.f = f;
    unsigned int r = x.i + 0x7fff + ((x.i >> 16) & 1);
    return (unsigned short)(r >> 16);
}
__device__ __forceinline__ unsigned short rhu(float f) {  // round-half-up, 2 VALU
    union { float f; unsigned int i; } x; x.f = f;
    return (unsigned short)((x.i + 0x8000) >> 16);
}

// async 16B global->LDS DMA (lane i writes lds_base + i*16; LDS base wave-uniform)
__device__ __forceinline__ void dma16(const void* g, void* l) {
    __builtin_amdgcn_global_load_lds((const __attribute__((address_space(1))) void*)g,
                                     (__attribute__((address_space(3))) void*)l,
                                     16, 0, 0);
}

// ---------------------------------------------------------------------------
// Fused aux (unchanged). grid=(64,8,3): z=0 Q-proj, z=1 K-proj, z=2 V cvt.
// ---------------------------------------------------------------------------
__global__ __launch_bounds__(256) void aux_kernel(
    const float* __restrict__ qimg, const float* __restrict__ kimg,
    const float* __restrict__ vimg,
    const float* __restrict__ Wq, const float* __restrict__ bq,
    const float* __restrict__ Wk, const float* __restrict__ bk,
    unsigned short* __restrict__ Qbuf, unsigned short* __restrict__ Kbuf,
    unsigned short* __restrict__ Vbuf)
{
    const int tid = threadIdx.x;
    const int z   = blockIdx.z;

    if (z == 2) {
        const size_t base = ((size_t)blockIdx.y * 64 + blockIdx.x) * 8192 + tid * 4;
        #pragma unroll
        for (int it = 0; it < 8; ++it) {
            const size_t i = base + (size_t)it * 1024;
            float4 v = *(const float4*)(vimg + i);
            ushort4 o;
            o.x = f2b(v.x); o.y = f2b(v.y); o.z = f2b(v.z); o.w = f2b(v.w);
            *(ushort4*)(Vbuf + i) = o;
        }
        return;
    }

    __shared__ float ilds[128 * 69];

    const float* img  = (z == 0) ? qimg : kimg;
    const float* Wf   = (z == 0) ? Wq : Wk;
    const float* bias = (z == 0) ? bq : bk;
    unsigned short* outTok = (z == 0) ? Qbuf : Kbuf;

    const int wave = tid >> 6;
    const int lane = tid & 63;
    const int l15  = lane & 15;
    const int quad = lane >> 4;
    const int b     = blockIdx.y;
    const int stile = blockIdx.x;

    const float* gbase = img + (size_t)b * CC * SS + stile * 64;
    #pragma unroll
    for (int i = 0; i < 8; ++i) {
        const int l = tid + 256 * i;
        const int row = l >> 4, col = (l & 15) * 4;
        float4 v = *(const float4*)(gbase + (size_t)row * SS + col);
        float* d = ilds + row * 69 + col;
        d[0] = v.x; d[1] = v.y; d[2] = v.z; d[3] = v.w;
    }
    __syncthreads();

    const int tcol = wave * 16 + l15;
    sh8 a[4];
    #pragma unroll
    for (int kk = 0; kk < 4; ++kk)
        #pragma unroll
        for (int j = 0; j < 8; ++j)
            a[kk][j] = (short)rhu(ilds[(32 * kk + quad * 8 + j) * 69 + tcol]);

    f32x4 acc[8];
    #pragma unroll
    for (int nt = 0; nt < 8; ++nt) acc[nt] = (f32x4){0.f, 0.f, 0.f, 0.f};

    #pragma unroll
    for (int nt = 0; nt < 8; ++nt) {
        const float* wp = Wf + (size_t)(16 * nt + l15) * CC + quad * 8;
        #pragma unroll
        for (int kk = 0; kk < 4; ++kk) {
            float4 w0 = *(const float4*)(wp + 32 * kk);
            float4 w1 = *(const float4*)(wp + 32 * kk + 4);
            sh8 bfr;
            bfr[0] = (short)rhu(w0.x); bfr[1] = (short)rhu(w0.y);
            bfr[2] = (short)rhu(w0.z); bfr[3] = (short)rhu(w0.w);
            bfr[4] = (short)rhu(w1.x); bfr[5] = (short)rhu(w1.y);
            bfr[6] = (short)rhu(w1.z); bfr[7] = (short)rhu(w1.w);
            acc[nt] = __builtin_amdgcn_mfma_f32_16x16x32_bf16(a[kk], bfr, acc[nt], 0, 0, 0);
        }
    }

    #pragma unroll
    for (int nt = 0; nt < 8; ++nt) {
        const int o = 16 * nt + l15;
        const float bv = bias[o];
        #pragma unroll
        for (int r = 0; r < 4; ++r) {
            const int s = stile * 64 + wave * 16 + quad * 4 + r;
            outTok[((size_t)b * SS + s) * CC + o] = f2b(acc[nt][r] + bv);
        }
    }
}

// ---------------------------------------------------------------------------
// Flash attention: 32x32x16 MFMA, per-wave P + partial-O, ONE barrier/iter,
// R8-style linear-coalesced DMA with K/V double-buffer (full-iter cover).
// Wave w: qh=w>>1 (32 q-rows), kth=w&1 (32-kt slice). PV accumulates partial
// O(32q x 128ch) over the wave's kt slice; halves merged once in epilogue.
// LDS map:
//   [0,16K) kb0 [16K,32K) kb1 : 64 tok x 256 B, chunk swizzle ^(tok&15)
//   [32K,48K) vb0 [48K,64K) vb1 : 128 ch x 128 B, chunk swizzle ^(ch&7)
//   [64K, 64K+10240) P : per-wave 32 q x 80 B (64 data + 16 pad)
//   [75776, 76032) lsums1 : float[2][32] (kth=1 partial row sums)
//   epilogue: oPart fp32[2][32][128] aliases [0,32K); oLds[64][133] at 32K.
// ---------------------------------------------------------------------------
__global__ __launch_bounds__(256, 2) void attn_kernel(
    const unsigned short* __restrict__ Qbuf,  // (B,S,C) bf16 token-major
    const unsigned short* __restrict__ Kbuf,  // (B,S,C) bf16 token-major
    const unsigned short* __restrict__ Vbuf,  // (B,C,S) bf16 channel-major
    float* __restrict__ out)                  // (B,C,S) fp32 channel-major
{
    __shared__ __align__(16) unsigned char smem[76032];

    const int tid  = threadIdx.x;
    const int wave = tid >> 6;
    const int lane = tid & 63;
    const int l31  = lane & 31;
    const int h    = lane >> 5;
    const int qh   = wave >> 1;
    const int kth  = wave & 1;
    const int b     = blockIdx.y;
    const int qtile = blockIdx.x;

    unsigned char* pw = smem + 65536 + wave * 2560;   // 32 rows x 80 B
    float* lsums1 = (float*)(smem + 75776);           // [qh][q31], kth=1 only

    const char* kbp = (const char*)(Kbuf + (size_t)b * SS * CC);
    const char* vbp = (const char*)(Vbuf + (size_t)b * CC * SS);

    // Q A-frags (32 q-rows): m=l31, k=16*ks+8*h+j  (layout verified in R9)
    sh8 aq[8];
    {
        const unsigned short* qp =
            Qbuf + ((size_t)b * SS + qtile * 64 + 32 * qh + l31) * CC + 8 * h;
        #pragma unroll
        for (int ks = 0; ks < 8; ++ks) aq[ks] = *(const sh8*)(qp + 16 * ks);
    }

    // DMA source offsets: K tokens swizzled ^(tok&15), V channels ^(ch&7);
    // global side stays contiguous per row (coalesced), LDS dst lane-linear.
    int kGO[4], vGO[4];
    #pragma unroll
    for (int j = 0; j < 4; ++j) {
        const int krow = wave * 16 + j * 4 + (lane >> 4);
        kGO[j] = krow * 256 + (((lane & 15) ^ (krow & 15)) << 4);
        const int vrow = (wave * 4 + j) * 8 + (lane >> 3);
        vGO[j] = vrow * 8192 + (((lane & 7) ^ ((lane >> 3) & 7)) << 4);
    }

    f32x16 oacc[4];
    #pragma unroll
    for (int ct = 0; ct < 4; ++ct)
        #pragma unroll
        for (int r = 0; r < 16; ++r) oacc[ct][r] = 0.f;
    float lsum[16];
    #pragma unroll
    for (int r = 0; r < 16; ++r) lsum[r] = 0.f;

    // prologue: stage tile 0 into buffer 0
    #pragma unroll
    for (int j = 0; j < 4; ++j) {
        dma16(kbp + kGO[j], smem + (wave * 4 + j) * 1024);
        dma16(vbp + vGO[j], smem + 32768 + (wave * 4 + j) * 1024);
    }

    const int tok = 32 * kth + l31;   // this lane's K token row in the tile

    for (int it = 0; it < SS / KT; ++it) {
        const int cur = (it & 1) * 16384;
        unsigned char* kb = smem + cur;
        unsigned char* vb = smem + 32768 + cur;

        __syncthreads();   // tile(it) resident; WAR for the other buffer

        if (it + 1 < SS / KT) {
            const int nxt = 16384 - cur;
            const char* gk = kbp + (size_t)(it + 1) * 16384;
            const char* gv = vbp + (size_t)(it + 1) * 128;
            #pragma unroll
            for (int j = 0; j < 4; ++j) {
                dma16(gk + kGO[j], smem + nxt + (wave * 4 + j) * 1024);
                dma16(gv + vGO[j], smem + 32768 + nxt + (wave * 4 + j) * 1024);
            }
        }

        // --- S(32q x 32kt) = Q K^T : B-frag n=tok, k-chunk c=2ks+h ---
        f32x16 sacc;
        #pragma unroll
        for (int r = 0; r < 16; ++r) sacc[r] = 0.f;
        #pragma unroll
        for (int ks = 0; ks < 8; ++ks) {
            sh8 kf = *(const sh8*)(kb + tok * 256
                                      + (((2 * ks + h) ^ (l31 & 15)) << 4));
            sacc = __builtin_amdgcn_mfma_f32_32x32x16_bf16(aq[ks], kf, sacc, 0, 0, 0);
        }

        // --- softmax (no max) -> per-wave P[q31][kt_local=l31] ---
        #pragma unroll
        for (int reg = 0; reg < 16; ++reg) {
            float p = exp2f(sacc[reg] * SCL2);
            lsum[reg] += p;
            const int q31 = (reg & 3) + 8 * (reg >> 2) + 4 * h;
            *(unsigned short*)(pw + q31 * 80 + l31 * 2) = rhu(p);
        }

        // --- partial O(32q x 128ch) += P V  (own kt slice; no barrier) ---
        #pragma unroll
        for (int step = 0; step < 2; ++step) {
            sh8 ap = *(const sh8*)(pw + l31 * 80 + 32 * step + 16 * h);
            const int ck = 4 * kth + 2 * step + h;   // kt chunk in V rows
            #pragma unroll
            for (int ct = 0; ct < 4; ++ct) {
                const int ch = 32 * ct + l31;
                sh8 bv = *(const sh8*)(vb + ch * 128 + ((ck ^ (l31 & 7)) << 4));
                oacc[ct] = __builtin_amdgcn_mfma_f32_32x32x16_bf16(ap, bv, oacc[ct], 0, 0, 0);
            }
        }
    }

    // --- reduce lsum over this wave's 32 kt (within each 32-lane half) ---
    #pragma unroll
    for (int reg = 0; reg < 16; ++reg) {
        float v = lsum[reg];
        #pragma unroll
        for (int m = 16; m >= 1; m >>= 1) v += __shfl_xor(v, m, 64);
        lsum[reg] = v;
    }

    __syncthreads();   // all K/V/P reads done; smem reusable

    // --- kth=1 waves publish partial O (fp32) + partial lsum ---
    if (kth) {
        float* op = (float*)smem + qh * 4096;   // [32 q][128 ch]
        #pragma unroll
        for (int ct = 0; ct < 4; ++ct)
            #pragma unroll
            for (int reg = 0; reg < 16; ++reg) {
                const int q31 = (reg & 3) + 8 * (reg >> 2) + 4 * h;
                op[q31 * 128 + 32 * ct + l31] = oacc[ct][reg];
            }
        if (l31 == 0)
            #pragma unroll
            for (int reg = 0; reg < 16; ++reg) {
                const int q31 = (reg & 3) + 8 * (reg >> 2) + 4 * h;
                lsums1[qh * 32 + q31] = lsum[reg];
            }
    }
    __syncthreads();

    // --- kth=0 waves merge, normalize, add residual, stage to oLds ---
    float* oLds = (float*)(smem + 32768);   // [64][133]
    if (!kth) {
        const float* op = (const float*)smem + qh * 4096;
        #pragma unroll
        for (int reg = 0; reg < 16; ++reg) {
            const int q31  = (reg & 3) + 8 * (reg >> 2) + 4 * h;
            const int qloc = 32 * qh + q31;
            const float rinv = 1.f / (lsum[reg] + lsums1[qh * 32 + q31]);
            #pragma unroll
            for (int ct = 0; ct < 4; ++ct) {
                const int ch = 32 * ct + l31;
                const float resid =
                    b2f(Qbuf[((size_t)b * SS + qtile * 64 + qloc) * CC + ch]);
                oLds[qloc * 133 + ch] =
                    (oacc[ct][reg] + op[q31 * 128 + ch]) * rinv + resid;
            }
        }
    }
    __syncthreads();

    // --- coalesced transpose write (fp32 channel-major) ---
    for (int idx = tid; idx < 64 * 128; idx += 256) {
        const int c = idx >> 6, q = idx & 63;
        out[((size_t)b * CC + c) * SS + qtile * 64 + q] = oLds[q * 133 + c];
    }
}

extern "C" void kernel_launch(void* const* d_in, const int* in_sizes, int n_in,
                              void* d_out, int out_size, void* d_ws, size_t ws_size,
                              hipStream_t stream) {
    const float* qimg = (const float*)d_in[0];
    const float* kimg = (const float*)d_in[1];
    const float* vimg = (const float*)d_in[2];
    const float* Wq   = (const float*)d_in[3];
    const float* bq   = (const float*)d_in[4];
    const float* Wk   = (const float*)d_in[5];
    const float* bk   = (const float*)d_in[6];
    float* out = (float*)d_out;

    unsigned short* Qbuf = (unsigned short*)d_ws;                    // 8.39 MB
    unsigned short* Kbuf = Qbuf + (size_t)BB * SS * CC;              // 8.39 MB
    unsigned short* Vbuf = Kbuf + (size_t)BB * SS * CC;              // 8.39 MB

    aux_kernel<<<dim3(SS / 64, BB, 3), 256, 0, stream>>>(
        qimg, kimg, vimg, Wq, bq, Wk, bk, Qbuf, Kbuf, Vbuf);
    attn_kernel<<<dim3(SS / 64, BB), 256, 0, stream>>>(Qbuf, Kbuf, Vbuf, out);
}